// Round 8
// baseline (259.371 us; speedup 1.0000x reference)
//
#include <hip/hip_runtime.h>
#include <hip/hip_bf16.h>

// ---------- types ----------
typedef short bf16x8 __attribute__((ext_vector_type(8)));
typedef float f32x4 __attribute__((ext_vector_type(4)));

#define NB 4
#define C 256
#define HW 4096
#define NROWS (NB * HW)   // 16384
#define EPSF 1e-5f

// ---------- helpers ----------
__device__ __forceinline__ unsigned short f2bf(float f) {
    unsigned int u = __float_as_uint(f);
    unsigned int r = u + 0x7fffu + ((u >> 16) & 1u);
    return (unsigned short)(r >> 16);
}
__device__ __forceinline__ float bf2f(unsigned int h) {
    return __uint_as_float(h << 16);
}
__device__ __forceinline__ void unpack8(uint4 u, float* v) {
    unsigned int w0 = u.x, w1 = u.y, w2 = u.z, w3 = u.w;
    v[0] = bf2f(w0 & 0xffffu); v[1] = bf2f(w0 >> 16);
    v[2] = bf2f(w1 & 0xffffu); v[3] = bf2f(w1 >> 16);
    v[4] = bf2f(w2 & 0xffffu); v[5] = bf2f(w2 >> 16);
    v[6] = bf2f(w3 & 0xffffu); v[7] = bf2f(w3 >> 16);
}
__device__ __forceinline__ float waveReduceSum(float v) {
    for (int off = 32; off > 0; off >>= 1) v += __shfl_xor(v, off);
    return v;
}
// async global->LDS 16B copy; lds ptr must be wave-uniform-base + lane*16
typedef __attribute__((address_space(1))) const unsigned int glb_cu;
typedef __attribute__((address_space(3))) unsigned int lds_u;
__device__ __forceinline__ void async_copy16(const unsigned short* g, unsigned short* l) {
    __builtin_amdgcn_global_load_lds((glb_cu*)g, (lds_u*)l, 16, 0, 0);
}

// ---------- K1: per-channel mean of y ----------
__global__ __launch_bounds__(256) void mu_kernel(const float* __restrict__ y,
                                                 float* __restrict__ mu) {
    int c = blockIdx.x;
    int tid = threadIdx.x;
    float s = 0.f;
    const float* base = y + (size_t)c * HW;
    for (int n = 0; n < NB; n++) {
        const float* bn = base + (size_t)n * C * HW;
        for (int i = tid; i < HW; i += 256) s += bn[i];
    }
    s = waveReduceSum(s);
    __shared__ float red[4];
    int lane = tid & 63, wave = tid >> 6;
    if (lane == 0) red[wave] = s;
    __syncthreads();
    if (tid == 0) mu[c] = (red[0] + red[1] + red[2] + red[3]) * (1.0f / 16384.0f);
}

// ---------- K2: center, L2-normalize over C, transpose to (n,p,c) bf16 ----------
#define TP 32
#define TSTRIDE 257
__global__ __launch_bounds__(256) void prep_kernel(const float* __restrict__ x,
                                                   const float* __restrict__ y,
                                                   const float* __restrict__ mu,
                                                   unsigned short* __restrict__ Xn,
                                                   unsigned short* __restrict__ Yn) {
    __shared__ float smu[C];
    __shared__ float tile[TP * TSTRIDE];
    __shared__ float red[8 * 32];
    __shared__ float invn[TP];
    int tid = threadIdx.x;
    smu[tid] = mu[tid];
    int blk = blockIdx.x;
    int n = blk >> 7;                // 128 blocks per batch
    int p0 = (blk & 127) * TP;
    int tp = tid & 31, cc = tid >> 5;
    __syncthreads();
    for (int pass = 0; pass < 2; pass++) {
        const float* in = pass ? y : x;
        unsigned short* out = pass ? Yn : Xn;
        const float* base = in + (size_t)n * C * HW + p0 + tp;
        float ssq = 0.f;
        for (int c = cc; c < C; c += 8) {
            float v = base[(size_t)c * HW] - smu[c];
            tile[tp * TSTRIDE + c] = v;
            ssq += v * v;
        }
        red[cc * 32 + tp] = ssq;
        __syncthreads();
        if (tid < 32) {
            float s = 0.f;
            for (int k = 0; k < 8; k++) s += red[k * 32 + tid];
            invn[tid] = rsqrtf(s);
        }
        __syncthreads();
        int c2 = (tid & 127) * 2;
        int pp = tid >> 7;
        for (int p = pp; p < TP; p += 2) {
            float inv = invn[p];
            unsigned short b0 = f2bf(tile[p * TSTRIDE + c2] * inv);
            unsigned short b1 = f2bf(tile[p * TSTRIDE + c2 + 1] * inv);
            unsigned int pack = (unsigned int)b0 | ((unsigned int)b1 << 16);
            ((unsigned int*)out)[(size_t)(n * HW + p0 + p) * (C / 2) + (c2 >> 1)] = pack;
        }
        __syncthreads();
    }
}

// ---------- K3: batched GEMM cos = Xn * Yn^T (R6 structure) + row-max partials ----------
// BK=128, 2 staging stages, 64 KB LDS, 2 blocks/CU (R7's BK=64/8-barrier variant
// regressed: MfmaUtil 25->21). Epilogue adds per-(row,qtile) max: data already
// in registers for the store; max + 4 shuffles + 1 conditional scalar store.
#define EPSTRIDE 136
__global__ __launch_bounds__(256, 2) void gemm_cos(const unsigned short* __restrict__ Xn,
                                                   const unsigned short* __restrict__ Yn,
                                                   unsigned short* __restrict__ Cos,
                                                   float* __restrict__ rowmaxp) {
    __shared__ unsigned short lds_us[32768];   // 64 KB: A[16K ushorts] B[16K]
    int n = blockIdx.z;
    int qb = blockIdx.x;
    int pBase = blockIdx.y * 128, qBase = qb * 128;
    const unsigned short* Ab = Xn + ((size_t)n * HW + pBase) * C;
    const unsigned short* Bb = Yn + ((size_t)n * HW + qBase) * C;
    int tid = threadIdx.x, lane = tid & 63, wave = tid >> 6;
    int wm = (wave >> 1) * 64, wn = (wave & 1) * 64;
    int mrow = lane & 15, quad = lane >> 4;

    f32x4 acc[4][4];
#pragma unroll
    for (int i = 0; i < 4; i++)
#pragma unroll
        for (int j = 0; j < 4; j++) acc[i][j] = (f32x4){0.f, 0.f, 0.f, 0.f};

#pragma unroll
    for (int h = 0; h < 2; h++) {
#pragma unroll
        for (int mat = 0; mat < 2; mat++) {
            const unsigned short* g = mat ? Bb : Ab;
            unsigned short* lbase = lds_us + mat * 16384;
#pragma unroll
            for (int t = 0; t < 8; t++) {
                int slot = t * 256 + tid;           // 0..2047
                int r = slot >> 4, cl = slot & 15;
                int c = h * 16 + (cl ^ (r & 15));   // global 16B-chunk index
                async_copy16(g + (size_t)r * C + c * 8, lbase + slot * 8);
            }
        }
        __syncthreads();
#pragma unroll
        for (int kkl = 0; kkl < 4; kkl++) {
            int cl4 = kkl * 4 + quad;
            int clp = cl4 ^ mrow;
            bf16x8 af[4], bfr[4];
#pragma unroll
            for (int i = 0; i < 4; i++) {
                af[i]  = *(const bf16x8*)(lds_us + (wm + i * 16 + mrow) * 128 + clp * 8);
                bfr[i] = *(const bf16x8*)(lds_us + 16384 + (wn + i * 16 + mrow) * 128 + clp * 8);
            }
#pragma unroll
            for (int i = 0; i < 4; i++)
#pragma unroll
                for (int j = 0; j < 4; j++)
                    acc[i][j] = __builtin_amdgcn_mfma_f32_16x16x32_bf16(af[i], bfr[j], acc[i][j], 0, 0, 0);
        }
        __syncthreads();
    }

    // ---- epilogue: transpose through LDS, coalesced stores + rowmax partials ----
    unsigned short* epb = lds_us;  // 128 x EPSTRIDE bf16 = 34 KB
    int col = lane & 15, quad4 = quad * 4;
#pragma unroll
    for (int i = 0; i < 4; i++)
#pragma unroll
        for (int j = 0; j < 4; j++)
#pragma unroll
            for (int r = 0; r < 4; r++)
                epb[(wm + i * 16 + quad4 + r) * EPSTRIDE + wn + j * 16 + col] = f2bf(acc[i][j][r]);
    __syncthreads();
    unsigned short* Crow = Cos + (size_t)n * HW * HW;
#pragma unroll
    for (int it = 0; it < 8; it++) {
        int e = it * 2048 + tid * 8;
        int r = e >> 7, cg = e & 127;
        uint4 o = *(const uint4*)(epb + r * EPSTRIDE + cg);
        *(uint4*)(Crow + (size_t)(pBase + r) * HW + qBase + cg) = o;
        float v[8];
        unpack8(o, v);
        float m = fmaxf(fmaxf(fmaxf(v[0], v[1]), fmaxf(v[2], v[3])),
                        fmaxf(fmaxf(v[4], v[5]), fmaxf(v[6], v[7])));
        m = fmaxf(m, __shfl_xor(m, 1));
        m = fmaxf(m, __shfl_xor(m, 2));
        m = fmaxf(m, __shfl_xor(m, 4));
        m = fmaxf(m, __shfl_xor(m, 8));
        if ((tid & 15) == 0)
            rowmaxp[(size_t)qb * NROWS + n * HW + pBase + r] = m;
    }
}

// ---------- K4: expsum + column logit-max, 2-global-pass streaming, low-VGPR ----------
// Pass A streams rows one at a time (live ~60 VGPR) for exp-rowsums; pass B
// re-reads the same rows (Cos is L3-resident: 128 MB < 256 MB) for the column
// logit-max. Inlines alpha computation from rowmaxp (one launch fewer).
__global__ __launch_bounds__(256, 4) void rowcol(const unsigned short* __restrict__ Cos,
                                                 const float* __restrict__ rowmaxp,
                                                 unsigned short* __restrict__ partial) {
    int n = blockIdx.y, chunk = blockIdx.x;   // 0..511, 8 rows each
    int tid = threadIdx.x, lane = tid & 63, wave = tid >> 6;
    int row0 = n * HW + chunk * 8;
    const unsigned short* rowbase = Cos + (size_t)row0 * HW;
    __shared__ float salpha[8], sbase[8];
    __shared__ float sval[8][4];

    // inline rowred: alpha from 32 qtile-max partials per row
    {
        int r = tid >> 5, qb = tid & 31;
        float m = rowmaxp[(size_t)qb * NROWS + row0 + r];
#pragma unroll
        for (int off = 16; off > 0; off >>= 1) m = fmaxf(m, __shfl_xor(m, off));
        if (qb == 0) {
            float a = 2.0f / ((1.0f - m) + EPSF);
            salpha[r] = a;
            sbase[r] = 2.0f - a;
        }
    }
    __syncthreads();

    // pass A: exp row-sums, one row at a time
    float s8[8];
#pragma unroll
    for (int r = 0; r < 8; r++) {
        const unsigned short* rp = rowbase + (size_t)r * HW;
        uint4 d0 = *(const uint4*)(rp + tid * 8);
        uint4 d1 = *(const uint4*)(rp + 2048 + tid * 8);
        float v[16];
        unpack8(d0, v); unpack8(d1, v + 8);
        float a = salpha[r], b = sbase[r];
        float s = 0.f;
#pragma unroll
        for (int k = 0; k < 16; k++) s += __expf(fmaf(a, v[k], b));
        s8[r] = s;
    }
#pragma unroll
    for (int off = 32; off > 0; off >>= 1)
#pragma unroll
        for (int r = 0; r < 8; r++) s8[r] += __shfl_xor(s8[r], off);
    if (lane == 0)
#pragma unroll
        for (int r = 0; r < 8; r++) sval[r][wave] = s8[r];
    __syncthreads();

    float beta[8];
#pragma unroll
    for (int r = 0; r < 8; r++) {
        float S = sval[r][0] + sval[r][1] + sval[r][2] + sval[r][3];
        beta[r] = sbase[r] - __logf(S);
    }

    // pass B: column logit-max (re-read from L3)
    float cmax[16];
#pragma unroll
    for (int k = 0; k < 16; k++) cmax[k] = -1e30f;
#pragma unroll
    for (int r = 0; r < 8; r++) {
        const unsigned short* rp = rowbase + (size_t)r * HW;
        uint4 d0 = *(const uint4*)(rp + tid * 8);
        uint4 d1 = *(const uint4*)(rp + 2048 + tid * 8);
        float v[16];
        unpack8(d0, v); unpack8(d1, v + 8);
        float a = salpha[r], b = beta[r];
#pragma unroll
        for (int k = 0; k < 16; k++) cmax[k] = fmaxf(cmax[k], fmaf(a, v[k], b));
    }

    unsigned short* outp = partial + ((size_t)(n * 512 + chunk)) * HW;
    uint4 o0, o1;
    o0.x = (unsigned int)f2bf(cmax[0]) | ((unsigned int)f2bf(cmax[1]) << 16);
    o0.y = (unsigned int)f2bf(cmax[2]) | ((unsigned int)f2bf(cmax[3]) << 16);
    o0.z = (unsigned int)f2bf(cmax[4]) | ((unsigned int)f2bf(cmax[5]) << 16);
    o0.w = (unsigned int)f2bf(cmax[6]) | ((unsigned int)f2bf(cmax[7]) << 16);
    o1.x = (unsigned int)f2bf(cmax[8]) | ((unsigned int)f2bf(cmax[9]) << 16);
    o1.y = (unsigned int)f2bf(cmax[10]) | ((unsigned int)f2bf(cmax[11]) << 16);
    o1.z = (unsigned int)f2bf(cmax[12]) | ((unsigned int)f2bf(cmax[13]) << 16);
    o1.w = (unsigned int)f2bf(cmax[14]) | ((unsigned int)f2bf(cmax[15]) << 16);
    *(uint4*)(outp + tid * 8) = o0;
    *(uint4*)(outp + 2048 + tid * 8) = o1;
}

// ---------- K5: merged column reduction: max over 512 chunks -> exp -> sum ----------
// grid (16, NB): block owns 256 q; wave w covers chunks w,w+4,...; lane owns
// 4 q (uint2). LDS combine across waves, exp, block sum, one atomicAdd/block.
__global__ __launch_bounds__(256) void colmerge(const unsigned short* __restrict__ partial,
                                                float* __restrict__ cxsum) {
    int n = blockIdx.y, qt = blockIdx.x;
    int tid = threadIdx.x, lane = tid & 63, wave = tid >> 6;
    const unsigned short* p = partial + (size_t)n * 512 * HW + qt * 256 + lane * 4;
    float m[4] = {-1e30f, -1e30f, -1e30f, -1e30f};
    for (int c = wave; c < 512; c += 4) {
        uint2 u = *(const uint2*)(p + (size_t)c * HW);
        m[0] = fmaxf(m[0], bf2f(u.x & 0xffffu));
        m[1] = fmaxf(m[1], bf2f(u.x >> 16));
        m[2] = fmaxf(m[2], bf2f(u.y & 0xffffu));
        m[3] = fmaxf(m[3], bf2f(u.y >> 16));
    }
    __shared__ float lm[4][64][4];
#pragma unroll
    for (int k = 0; k < 4; k++) lm[wave][lane][k] = m[k];
    __syncthreads();
    if (wave == 0) {
        float s = 0.f;
#pragma unroll
        for (int k = 0; k < 4; k++) {
            float mm = fmaxf(fmaxf(lm[0][lane][k], lm[1][lane][k]),
                             fmaxf(lm[2][lane][k], lm[3][lane][k]));
            s += __expf(mm);
        }
        s = waveReduceSum(s);
        if (lane == 0) atomicAdd(&cxsum[n], s);
    }
}

// ---------- K6: final loss ----------
__global__ void finalize(const float* __restrict__ cxsum, float* __restrict__ out) {
    if (threadIdx.x == 0 && blockIdx.x == 0) {
        float loss = 0.f;
        for (int n = 0; n < NB; n++) {
            float cx = cxsum[n] * (1.0f / 4096.0f);
            loss += -logf(cx + EPSF);
        }
        out[0] = loss * 0.25f;
    }
}

// ---------- launch ----------
extern "C" void kernel_launch(void* const* d_in, const int* in_sizes, int n_in,
                              void* d_out, int out_size, void* d_ws, size_t ws_size,
                              hipStream_t stream) {
    const float* x = (const float*)d_in[0];
    const float* y = (const float*)d_in[1];
    float* out = (float*)d_out;
    char* ws = (char*)d_ws;

    float* mu               = (float*)(ws + 0);                   // 1 KiB
    float* cxsum            = (float*)(ws + 1024);                // 16 B
    float* rowmaxp          = (float*)(ws + 2097152);             // 2 MiB @ [2,4) MiB
    unsigned short* Xn      = (unsigned short*)(ws + 4194304);    // 8 MiB @ [4,12)
    unsigned short* Yn      = (unsigned short*)(ws + 12582912);   // 8 MiB @ [12,20)
    unsigned short* partial = (unsigned short*)(ws + 4194304);    // 16 MiB bf16 (aliases Xn+Yn)
    unsigned short* Cos     = (unsigned short*)(ws + 20971520);   // 128 MiB @ [20,148)

    hipMemsetAsync(cxsum, 0, NB * sizeof(float), stream);

    mu_kernel<<<C, 256, 0, stream>>>(y, mu);
    prep_kernel<<<NROWS / TP, 256, 0, stream>>>(x, y, mu, Xn, Yn);
    gemm_cos<<<dim3(HW / 128, HW / 128, NB), 256, 0, stream>>>(Xn, Yn, Cos, rowmaxp);
    rowcol<<<dim3(512, NB), 256, 0, stream>>>(Cos, rowmaxp, partial);
    colmerge<<<dim3(16, NB), 256, 0, stream>>>(partial, cxsum);
    finalize<<<1, 64, 0, stream>>>(cxsum, out);
}

// Round 9
// 241.847 us; speedup vs baseline: 1.0725x; 1.0725x over previous
//
#include <hip/hip_runtime.h>
#include <hip/hip_bf16.h>

// ---------- types ----------
typedef short bf16x8 __attribute__((ext_vector_type(8)));
typedef float f32x4 __attribute__((ext_vector_type(4)));

#define NB 4
#define C 256
#define HW 4096
#define NROWS (NB * HW)   // 16384
#define EPSF 1e-5f

// ---------- helpers ----------
__device__ __forceinline__ unsigned short f2bf(float f) {
    unsigned int u = __float_as_uint(f);
    unsigned int r = u + 0x7fffu + ((u >> 16) & 1u);
    return (unsigned short)(r >> 16);
}
__device__ __forceinline__ float bf2f(unsigned int h) {
    return __uint_as_float(h << 16);
}
__device__ __forceinline__ void unpack8(uint4 u, float* v) {
    unsigned int w0 = u.x, w1 = u.y, w2 = u.z, w3 = u.w;
    v[0] = bf2f(w0 & 0xffffu); v[1] = bf2f(w0 >> 16);
    v[2] = bf2f(w1 & 0xffffu); v[3] = bf2f(w1 >> 16);
    v[4] = bf2f(w2 & 0xffffu); v[5] = bf2f(w2 >> 16);
    v[6] = bf2f(w3 & 0xffffu); v[7] = bf2f(w3 >> 16);
}
__device__ __forceinline__ float waveReduceSum(float v) {
    for (int off = 32; off > 0; off >>= 1) v += __shfl_xor(v, off);
    return v;
}
// async global->LDS 16B copy; lds ptr must be wave-uniform-base + lane*16
typedef __attribute__((address_space(1))) const unsigned int glb_cu;
typedef __attribute__((address_space(3))) unsigned int lds_u;
__device__ __forceinline__ void async_copy16(const unsigned short* g, unsigned short* l) {
    __builtin_amdgcn_global_load_lds((glb_cu*)g, (lds_u*)l, 16, 0, 0);
}

// ---------- K1: per-channel mean of y ----------
__global__ __launch_bounds__(256) void mu_kernel(const float* __restrict__ y,
                                                 float* __restrict__ mu) {
    int c = blockIdx.x;
    int tid = threadIdx.x;
    float s = 0.f;
    const float* base = y + (size_t)c * HW;
    for (int n = 0; n < NB; n++) {
        const float* bn = base + (size_t)n * C * HW;
        for (int i = tid; i < HW; i += 256) s += bn[i];
    }
    s = waveReduceSum(s);
    __shared__ float red[4];
    int lane = tid & 63, wave = tid >> 6;
    if (lane == 0) red[wave] = s;
    __syncthreads();
    if (tid == 0) mu[c] = (red[0] + red[1] + red[2] + red[3]) * (1.0f / 16384.0f);
}

// ---------- K2: center, L2-normalize over C, transpose to (n,p,c) bf16 ----------
#define TP 32
#define TSTRIDE 257
__global__ __launch_bounds__(256) void prep_kernel(const float* __restrict__ x,
                                                   const float* __restrict__ y,
                                                   const float* __restrict__ mu,
                                                   unsigned short* __restrict__ Xn,
                                                   unsigned short* __restrict__ Yn) {
    __shared__ float smu[C];
    __shared__ float tile[TP * TSTRIDE];
    __shared__ float red[8 * 32];
    __shared__ float invn[TP];
    int tid = threadIdx.x;
    smu[tid] = mu[tid];
    int blk = blockIdx.x;
    int n = blk >> 7;                // 128 blocks per batch
    int p0 = (blk & 127) * TP;
    int tp = tid & 31, cc = tid >> 5;
    __syncthreads();
    for (int pass = 0; pass < 2; pass++) {
        const float* in = pass ? y : x;
        unsigned short* out = pass ? Yn : Xn;
        const float* base = in + (size_t)n * C * HW + p0 + tp;
        float ssq = 0.f;
        for (int c = cc; c < C; c += 8) {
            float v = base[(size_t)c * HW] - smu[c];
            tile[tp * TSTRIDE + c] = v;
            ssq += v * v;
        }
        red[cc * 32 + tp] = ssq;
        __syncthreads();
        if (tid < 32) {
            float s = 0.f;
            for (int k = 0; k < 8; k++) s += red[k * 32 + tid];
            invn[tid] = rsqrtf(s);
        }
        __syncthreads();
        int c2 = (tid & 127) * 2;
        int pp = tid >> 7;
        for (int p = pp; p < TP; p += 2) {
            float inv = invn[p];
            unsigned short b0 = f2bf(tile[p * TSTRIDE + c2] * inv);
            unsigned short b1 = f2bf(tile[p * TSTRIDE + c2 + 1] * inv);
            unsigned int pack = (unsigned int)b0 | ((unsigned int)b1 << 16);
            ((unsigned int*)out)[(size_t)(n * HW + p0 + p) * (C / 2) + (c2 >> 1)] = pack;
        }
        __syncthreads();
    }
}

// ---------- K3: batched GEMM cos = Xn * Yn^T (R6 structure) + rowmax from acc ----------
// BK=128, 2 staging stages, 64 KB LDS, 2 blocks/CU. Rowmax partials computed
// on f32 acc registers BEFORE pack/transpose (R8 lesson: post-transpose bf16
// unpack + dependent shuffles cost 13 us). Per wave: 64 q-columns -> slot
// qb*2 + (wave&1); 64 slots total.
#define EPSTRIDE 136
__global__ __launch_bounds__(256, 2) void gemm_cos(const unsigned short* __restrict__ Xn,
                                                   const unsigned short* __restrict__ Yn,
                                                   unsigned short* __restrict__ Cos,
                                                   float* __restrict__ rowmaxp) {
    __shared__ unsigned short lds_us[32768];   // 64 KB: A[16K ushorts] B[16K]
    int n = blockIdx.z;
    int qb = blockIdx.x;
    int pBase = blockIdx.y * 128, qBase = qb * 128;
    const unsigned short* Ab = Xn + ((size_t)n * HW + pBase) * C;
    const unsigned short* Bb = Yn + ((size_t)n * HW + qBase) * C;
    int tid = threadIdx.x, lane = tid & 63, wave = tid >> 6;
    int wm = (wave >> 1) * 64, wn = (wave & 1) * 64;
    int mrow = lane & 15, quad = lane >> 4;

    f32x4 acc[4][4];
#pragma unroll
    for (int i = 0; i < 4; i++)
#pragma unroll
        for (int j = 0; j < 4; j++) acc[i][j] = (f32x4){0.f, 0.f, 0.f, 0.f};

#pragma unroll
    for (int h = 0; h < 2; h++) {
#pragma unroll
        for (int mat = 0; mat < 2; mat++) {
            const unsigned short* g = mat ? Bb : Ab;
            unsigned short* lbase = lds_us + mat * 16384;
#pragma unroll
            for (int t = 0; t < 8; t++) {
                int slot = t * 256 + tid;           // 0..2047
                int r = slot >> 4, cl = slot & 15;
                int c = h * 16 + (cl ^ (r & 15));   // global 16B-chunk index
                async_copy16(g + (size_t)r * C + c * 8, lbase + slot * 8);
            }
        }
        __syncthreads();
#pragma unroll
        for (int kkl = 0; kkl < 4; kkl++) {
            int cl4 = kkl * 4 + quad;
            int clp = cl4 ^ mrow;
            bf16x8 af[4], bfr[4];
#pragma unroll
            for (int i = 0; i < 4; i++) {
                af[i]  = *(const bf16x8*)(lds_us + (wm + i * 16 + mrow) * 128 + clp * 8);
                bfr[i] = *(const bf16x8*)(lds_us + 16384 + (wn + i * 16 + mrow) * 128 + clp * 8);
            }
#pragma unroll
            for (int i = 0; i < 4; i++)
#pragma unroll
                for (int j = 0; j < 4; j++)
                    acc[i][j] = __builtin_amdgcn_mfma_f32_16x16x32_bf16(af[i], bfr[j], acc[i][j], 0, 0, 0);
        }
        __syncthreads();
    }

    int col = lane & 15, quad4 = quad * 4;

    // ---- rowmax partials from acc (f32, pre-pack): 16 independent chains ----
    {
        int slot = qb * 2 + (wave & 1);
        float* rmbase = rowmaxp + (size_t)slot * NROWS + n * HW + pBase + wm;
#pragma unroll
        for (int i = 0; i < 4; i++) {
            float rm[4];
#pragma unroll
            for (int reg = 0; reg < 4; reg++) {
                float m = fmaxf(fmaxf(acc[i][0][reg], acc[i][1][reg]),
                                fmaxf(acc[i][2][reg], acc[i][3][reg]));
                m = fmaxf(m, __shfl_xor(m, 1));
                m = fmaxf(m, __shfl_xor(m, 2));
                m = fmaxf(m, __shfl_xor(m, 4));
                m = fmaxf(m, __shfl_xor(m, 8));
                rm[reg] = m;
            }
            if (col == 0) {
                float4 o = {rm[0], rm[1], rm[2], rm[3]};
                *(float4*)(rmbase + i * 16 + quad4) = o;   // 16B-aligned
            }
        }
    }

    // ---- epilogue: transpose through LDS (bf16), coalesced dwordx4 stores ----
    unsigned short* epb = lds_us;  // 128 x EPSTRIDE bf16 = 34 KB
#pragma unroll
    for (int i = 0; i < 4; i++)
#pragma unroll
        for (int j = 0; j < 4; j++)
#pragma unroll
            for (int r = 0; r < 4; r++)
                epb[(wm + i * 16 + quad4 + r) * EPSTRIDE + wn + j * 16 + col] = f2bf(acc[i][j][r]);
    __syncthreads();
    unsigned short* Crow = Cos + (size_t)n * HW * HW;
#pragma unroll
    for (int it = 0; it < 8; it++) {
        int e = it * 2048 + tid * 8;
        int r = e >> 7, cg = e & 127;
        uint4 o = *(const uint4*)(epb + r * EPSTRIDE + cg);
        *(uint4*)(Crow + (size_t)(pBase + r) * HW + qBase + cg) = o;
    }
}

// ---------- K4: expsum + column logit-max (8 rows/block, reg-resident, 2 phases) ----------
// alpha comes from rowmaxp (64 q-tile slots) -> phase 1 eliminated.
__global__ __launch_bounds__(256, 3) void rowcol(const unsigned short* __restrict__ Cos,
                                                 const float* __restrict__ rowmaxp,
                                                 unsigned short* __restrict__ partial) {
    int n = blockIdx.y, chunk = blockIdx.x;   // 0..511, 8 rows each
    int tid = threadIdx.x, lane = tid & 63, wave = tid >> 6;
    int row0 = n * HW + chunk * 8;
    const unsigned short* rowbase = Cos + (size_t)row0 * HW;
    __shared__ float salpha[8], sbase[8];
    __shared__ float sval[8][4];

    // alpha from 64 slot-maxes per row (thread tid: row tid>>5, slots qs,qs+32)
    {
        int r = tid >> 5, qs = tid & 31;
        float m = fmaxf(rowmaxp[(size_t)qs * NROWS + row0 + r],
                        rowmaxp[(size_t)(qs + 32) * NROWS + row0 + r]);
#pragma unroll
        for (int off = 16; off > 0; off >>= 1) m = fmaxf(m, __shfl_xor(m, off));
        if (qs == 0) {
            float a = 2.0f / ((1.0f - m) + EPSF);
            salpha[r] = a;
            sbase[r] = 2.0f - a;
        }
    }
    __syncthreads();

    uint4 d[8][2];
#pragma unroll
    for (int r = 0; r < 8; r++) {
        const unsigned short* rp = rowbase + (size_t)r * HW;
        d[r][0] = *(const uint4*)(rp + tid * 8);
        d[r][1] = *(const uint4*)(rp + 2048 + tid * 8);
    }
    float alpha[8];
#pragma unroll
    for (int r = 0; r < 8; r++) alpha[r] = salpha[r];

    // phase A: exp row-sums (batched butterfly)
    float s8[8];
#pragma unroll
    for (int r = 0; r < 8; r++) {
        float v[16];
        unpack8(d[r][0], v); unpack8(d[r][1], v + 8);
        float b = sbase[r];
        float s = 0.f;
#pragma unroll
        for (int k = 0; k < 16; k++) s += __expf(fmaf(alpha[r], v[k], b));
        s8[r] = s;
    }
#pragma unroll
    for (int off = 32; off > 0; off >>= 1)
#pragma unroll
        for (int r = 0; r < 8; r++) s8[r] += __shfl_xor(s8[r], off);
    if (lane == 0)
#pragma unroll
        for (int r = 0; r < 8; r++) sval[r][wave] = s8[r];
    __syncthreads();

    // phase B: beta + column logit-max
    float cmax[16];
#pragma unroll
    for (int k = 0; k < 16; k++) cmax[k] = -1e30f;
#pragma unroll
    for (int r = 0; r < 8; r++) {
        float S = sval[r][0] + sval[r][1] + sval[r][2] + sval[r][3];
        float beta = sbase[r] - __logf(S);
        float v[16];
        unpack8(d[r][0], v); unpack8(d[r][1], v + 8);
#pragma unroll
        for (int k = 0; k < 16; k++) cmax[k] = fmaxf(cmax[k], fmaf(alpha[r], v[k], beta));
    }

    unsigned short* outp = partial + ((size_t)(n * 512 + chunk)) * HW;
    uint4 o0, o1;
    o0.x = (unsigned int)f2bf(cmax[0]) | ((unsigned int)f2bf(cmax[1]) << 16);
    o0.y = (unsigned int)f2bf(cmax[2]) | ((unsigned int)f2bf(cmax[3]) << 16);
    o0.z = (unsigned int)f2bf(cmax[4]) | ((unsigned int)f2bf(cmax[5]) << 16);
    o0.w = (unsigned int)f2bf(cmax[6]) | ((unsigned int)f2bf(cmax[7]) << 16);
    o1.x = (unsigned int)f2bf(cmax[8]) | ((unsigned int)f2bf(cmax[9]) << 16);
    o1.y = (unsigned int)f2bf(cmax[10]) | ((unsigned int)f2bf(cmax[11]) << 16);
    o1.z = (unsigned int)f2bf(cmax[12]) | ((unsigned int)f2bf(cmax[13]) << 16);
    o1.w = (unsigned int)f2bf(cmax[14]) | ((unsigned int)f2bf(cmax[15]) << 16);
    *(uint4*)(outp + tid * 8) = o0;
    *(uint4*)(outp + 2048 + tid * 8) = o1;
}

// ---------- K5: merged column reduction: max over 512 chunks -> exp -> sum ----------
// grid (16, NB); block owns 256 q; wave w covers chunks w, w+4, ...; direct
// per-block store (no atomics, no memset).
__global__ __launch_bounds__(256) void colmerge(const unsigned short* __restrict__ partial,
                                               float* __restrict__ csums) {
    int n = blockIdx.y, qt = blockIdx.x;
    int tid = threadIdx.x, lane = tid & 63, wave = tid >> 6;
    const unsigned short* p = partial + (size_t)n * 512 * HW + qt * 256 + lane * 4;
    float m[4] = {-1e30f, -1e30f, -1e30f, -1e30f};
    for (int c = wave; c < 512; c += 4) {
        uint2 u = *(const uint2*)(p + (size_t)c * HW);
        m[0] = fmaxf(m[0], bf2f(u.x & 0xffffu));
        m[1] = fmaxf(m[1], bf2f(u.x >> 16));
        m[2] = fmaxf(m[2], bf2f(u.y & 0xffffu));
        m[3] = fmaxf(m[3], bf2f(u.y >> 16));
    }
    __shared__ float lm[4][64][4];
#pragma unroll
    for (int k = 0; k < 4; k++) lm[wave][lane][k] = m[k];
    __syncthreads();
    if (wave == 0) {
        float s = 0.f;
#pragma unroll
        for (int k = 0; k < 4; k++) {
            float mm = fmaxf(fmaxf(lm[0][lane][k], lm[1][lane][k]),
                             fmaxf(lm[2][lane][k], lm[3][lane][k]));
            s += __expf(mm);
        }
        s = waveReduceSum(s);
        if (lane == 0) csums[n * 16 + qt] = s;
    }
}

// ---------- K6: final loss ----------
__global__ void finalize(const float* __restrict__ csums, float* __restrict__ out) {
    if (threadIdx.x == 0 && blockIdx.x == 0) {
        float loss = 0.f;
        for (int n = 0; n < NB; n++) {
            float S = 0.f;
            for (int t = 0; t < 16; t++) S += csums[n * 16 + t];
            float cx = S * (1.0f / 4096.0f);
            loss += -logf(cx + EPSF);
        }
        out[0] = loss * 0.25f;
    }
}

// ---------- launch ----------
extern "C" void kernel_launch(void* const* d_in, const int* in_sizes, int n_in,
                              void* d_out, int out_size, void* d_ws, size_t ws_size,
                              hipStream_t stream) {
    const float* x = (const float*)d_in[0];
    const float* y = (const float*)d_in[1];
    float* out = (float*)d_out;
    char* ws = (char*)d_ws;

    float* mu               = (float*)(ws + 0);                   // 1 KiB
    float* csums            = (float*)(ws + 1024);                // 256 B
    float* rowmaxp          = (float*)(ws + 2097152);             // 4 MiB @ [2,6) MiB
    unsigned short* Xn      = (unsigned short*)(ws + 6291456);    // 8 MiB @ [6,14)
    unsigned short* Yn      = (unsigned short*)(ws + 14680064);   // 8 MiB @ [14,22)
    unsigned short* partial = (unsigned short*)(ws + 6291456);    // 16 MiB bf16 (aliases Xn+Yn)
    unsigned short* Cos     = (unsigned short*)(ws + 23068672);   // 128 MiB @ [22,150)

    mu_kernel<<<C, 256, 0, stream>>>(y, mu);
    prep_kernel<<<NROWS / TP, 256, 0, stream>>>(x, y, mu, Xn, Yn);
    gemm_cos<<<dim3(HW / 128, HW / 128, NB), 256, 0, stream>>>(Xn, Yn, Cos, rowmaxp);
    rowcol<<<dim3(512, NB), 256, 0, stream>>>(Cos, rowmaxp, partial);
    colmerge<<<dim3(16, NB), 256, 0, stream>>>(partial, csums);
    finalize<<<1, 64, 0, stream>>>(csums, out);
}

// Round 11
// 200.349 us; speedup vs baseline: 1.2946x; 1.2071x over previous
//
#include <hip/hip_runtime.h>
#include <hip/hip_bf16.h>

// ---------- types ----------
typedef short bf16x8 __attribute__((ext_vector_type(8)));
typedef float f32x4 __attribute__((ext_vector_type(4)));

#define NB 4
#define C 256
#define HW 4096
#define NROWS (NB * HW)   // 16384
#define EPSF 1e-5f

// ---------- helpers ----------
__device__ __forceinline__ unsigned short f2bf(float f) {
    unsigned int u = __float_as_uint(f);
    unsigned int r = u + 0x7fffu + ((u >> 16) & 1u);
    return (unsigned short)(r >> 16);
}
// packed f32x2 -> bf16x2 (round-nearest-even), low=a high=b
__device__ __forceinline__ unsigned int pack2bf(float a, float b) {
    return (unsigned int)f2bf(a) | ((unsigned int)f2bf(b) << 16);
}
__device__ __forceinline__ float bf2f(unsigned int h) {
    return __uint_as_float(h << 16);
}
__device__ __forceinline__ void unpack8(uint4 u, float* v) {
    unsigned int w0 = u.x, w1 = u.y, w2 = u.z, w3 = u.w;
    v[0] = bf2f(w0 & 0xffffu); v[1] = bf2f(w0 >> 16);
    v[2] = bf2f(w1 & 0xffffu); v[3] = bf2f(w1 >> 16);
    v[4] = bf2f(w2 & 0xffffu); v[5] = bf2f(w2 >> 16);
    v[6] = bf2f(w3 & 0xffffu); v[7] = bf2f(w3 >> 16);
}
__device__ __forceinline__ float waveReduceSum(float v) {
    for (int off = 32; off > 0; off >>= 1) v += __shfl_xor(v, off);
    return v;
}
// async global->LDS 16B copy; lds ptr must be wave-uniform-base + lane*16
typedef __attribute__((address_space(1))) const unsigned int glb_cu;
typedef __attribute__((address_space(3))) unsigned int lds_u;
__device__ __forceinline__ void async_copy16(const unsigned short* g, unsigned short* l) {
    __builtin_amdgcn_global_load_lds((glb_cu*)g, (lds_u*)l, 16, 0, 0);
}

// ---------- K1: per-channel mean of y ----------
__global__ __launch_bounds__(256) void mu_kernel(const float* __restrict__ y,
                                                 float* __restrict__ mu) {
    int c = blockIdx.x;
    int tid = threadIdx.x;
    float s = 0.f;
    const float* base = y + (size_t)c * HW;
    for (int n = 0; n < NB; n++) {
        const float* bn = base + (size_t)n * C * HW;
        for (int i = tid; i < HW; i += 256) s += bn[i];
    }
    s = waveReduceSum(s);
    __shared__ float red[4];
    int lane = tid & 63, wave = tid >> 6;
    if (lane == 0) red[wave] = s;
    __syncthreads();
    if (tid == 0) mu[c] = (red[0] + red[1] + red[2] + red[3]) * (1.0f / 16384.0f);
}

// ---------- K2: center, L2-normalize over C, transpose to (n,p,c) bf16 ----------
#define TP 32
#define TSTRIDE 257
__global__ __launch_bounds__(256) void prep_kernel(const float* __restrict__ x,
                                                   const float* __restrict__ y,
                                                   const float* __restrict__ mu,
                                                   unsigned short* __restrict__ Xn,
                                                   unsigned short* __restrict__ Yn) {
    __shared__ float smu[C];
    __shared__ float tile[TP * TSTRIDE];
    __shared__ float red[8 * 32];
    __shared__ float invn[TP];
    int tid = threadIdx.x;
    smu[tid] = mu[tid];
    int blk = blockIdx.x;
    int n = blk >> 7;                // 128 blocks per batch
    int p0 = (blk & 127) * TP;
    int tp = tid & 31, cc = tid >> 5;
    __syncthreads();
    for (int pass = 0; pass < 2; pass++) {
        const float* in = pass ? y : x;
        unsigned short* out = pass ? Yn : Xn;
        const float* base = in + (size_t)n * C * HW + p0 + tp;
        float ssq = 0.f;
        for (int c = cc; c < C; c += 8) {
            float v = base[(size_t)c * HW] - smu[c];
            tile[tp * TSTRIDE + c] = v;
            ssq += v * v;
        }
        red[cc * 32 + tp] = ssq;
        __syncthreads();
        if (tid < 32) {
            float s = 0.f;
            for (int k = 0; k < 8; k++) s += red[k * 32 + tid];
            invn[tid] = rsqrtf(s);
        }
        __syncthreads();
        int c2 = (tid & 127) * 2;
        int pp = tid >> 7;
        for (int p = pp; p < TP; p += 2) {
            float inv = invn[p];
            unsigned int pack = pack2bf(tile[p * TSTRIDE + c2] * inv,
                                        tile[p * TSTRIDE + c2 + 1] * inv);
            ((unsigned int*)out)[(size_t)(n * HW + p0 + p) * (C / 2) + (c2 >> 1)] = pack;
        }
        __syncthreads();
    }
}

// ---------- K3: batched GEMM cos = Xn * Yn^T (operand-swapped) ----------
// A-operand = Y (q-rows), B-operand = X (p-rows): C-layout gives each lane 4
// CONSECUTIVE q per acc tile -> epilogue LDS transpose uses 16 ds_write_b64
// (packed) instead of 64 ds_write_b16 (R8/R9 lesson: epilogue serial
// VALU/LDS ops directly displace MFMA). BK=128, 64 KB LDS, 2 blocks/CU.
#define EPSTRIDE 136
__global__ __launch_bounds__(256, 2) void gemm_cos(const unsigned short* __restrict__ Xn,
                                                   const unsigned short* __restrict__ Yn,
                                                   unsigned short* __restrict__ Cos) {
    __shared__ unsigned short lds_us[32768];   // 64 KB: X[16K ushorts] Y[16K]
    int n = blockIdx.z;
    int pBase = blockIdx.y * 128, qBase = blockIdx.x * 128;
    const unsigned short* Xb = Xn + ((size_t)n * HW + pBase) * C;
    const unsigned short* Yb = Yn + ((size_t)n * HW + qBase) * C;
    int tid = threadIdx.x, lane = tid & 63, wave = tid >> 6;
    int wq = (wave >> 1) * 64, wp = (wave & 1) * 64;
    int mrow = lane & 15, quad = lane >> 4;

    f32x4 acc[4][4];   // acc[i][j]: q-block i, p-block j
#pragma unroll
    for (int i = 0; i < 4; i++)
#pragma unroll
        for (int j = 0; j < 4; j++) acc[i][j] = (f32x4){0.f, 0.f, 0.f, 0.f};

#pragma unroll
    for (int h = 0; h < 2; h++) {
#pragma unroll
        for (int mat = 0; mat < 2; mat++) {
            const unsigned short* g = mat ? Yb : Xb;
            unsigned short* lbase = lds_us + mat * 16384;
#pragma unroll
            for (int t = 0; t < 8; t++) {
                int slot = t * 256 + tid;           // 0..2047
                int r = slot >> 4, cl = slot & 15;
                int c = h * 16 + (cl ^ (r & 15));   // global 16B-chunk index
                async_copy16(g + (size_t)r * C + c * 8, lbase + slot * 8);
            }
        }
        __syncthreads();
#pragma unroll
        for (int kkl = 0; kkl < 4; kkl++) {
            int cl4 = kkl * 4 + quad;
            int clp = cl4 ^ mrow;
            bf16x8 af[4], bfr[4];
#pragma unroll
            for (int i = 0; i < 4; i++) {
                af[i]  = *(const bf16x8*)(lds_us + 16384 + (wq + i * 16 + mrow) * 128 + clp * 8); // Y rows (q)
                bfr[i] = *(const bf16x8*)(lds_us + (wp + i * 16 + mrow) * 128 + clp * 8);         // X rows (p)
            }
#pragma unroll
            for (int i = 0; i < 4; i++)
#pragma unroll
                for (int j = 0; j < 4; j++)
                    acc[i][j] = __builtin_amdgcn_mfma_f32_16x16x32_bf16(af[i], bfr[j], acc[i][j], 0, 0, 0);
        }
        __syncthreads();
    }

    // ---- epilogue: epb[p][q] via packed b64 writes, then coalesced stores ----
    unsigned short* epb = lds_us;  // 128 x EPSTRIDE bf16 = 34 KB
    int col = lane & 15, quad4 = quad * 4;
#pragma unroll
    for (int i = 0; i < 4; i++)
#pragma unroll
        for (int j = 0; j < 4; j++) {
            uint2 o;
            o.x = pack2bf(acc[i][j][0], acc[i][j][1]);
            o.y = pack2bf(acc[i][j][2], acc[i][j][3]);
            // p = wp + j*16 + col ; q = wq + i*16 + quad4 (+0..3 packed)
            *(uint2*)&epb[(wp + j * 16 + col) * EPSTRIDE + wq + i * 16 + quad4] = o;
        }
    __syncthreads();
    unsigned short* Crow = Cos + (size_t)n * HW * HW;
#pragma unroll
    for (int it = 0; it < 8; it++) {
        int e = it * 2048 + tid * 8;
        int r = e >> 7, cg = e & 127;
        uint4 o = *(const uint4*)(epb + r * EPSTRIDE + cg);
        *(uint4*)(Crow + (size_t)(pBase + r) * HW + qBase + cg) = o;
    }
}

// ---------- K4: fused row stats + column logit-max (R6: 8 rows/block, reg-resident) ----------
__global__ __launch_bounds__(256, 3) void rowcol(const unsigned short* __restrict__ Cos,
                                                 unsigned short* __restrict__ partial) {
    int n = blockIdx.y, chunk = blockIdx.x;   // 0..511, 8 rows each
    int tid = threadIdx.x, lane = tid & 63, wave = tid >> 6;
    const unsigned short* rowbase = Cos + ((size_t)n * HW + chunk * 8) * HW;
    __shared__ float redm[8][4];
    __shared__ float sval[8][4];

    uint4 d[8][2];
#pragma unroll
    for (int r = 0; r < 8; r++) {
        const unsigned short* rp = rowbase + (size_t)r * HW;
        d[r][0] = *(const uint4*)(rp + tid * 8);
        d[r][1] = *(const uint4*)(rp + 2048 + tid * 8);
    }

    // phase 1: row maxes (batched butterfly)
    float m8[8];
#pragma unroll
    for (int r = 0; r < 8; r++) {
        float v[16];
        unpack8(d[r][0], v); unpack8(d[r][1], v + 8);
        float m = v[0];
#pragma unroll
        for (int k = 1; k < 16; k++) m = fmaxf(m, v[k]);
        m8[r] = m;
    }
#pragma unroll
    for (int off = 32; off > 0; off >>= 1)
#pragma unroll
        for (int r = 0; r < 8; r++) m8[r] = fmaxf(m8[r], __shfl_xor(m8[r], off));
    if (lane == 0)
#pragma unroll
        for (int r = 0; r < 8; r++) redm[r][wave] = m8[r];
    __syncthreads();

    float alpha[8], basec[8];
#pragma unroll
    for (int r = 0; r < 8; r++) {
        float M = fmaxf(fmaxf(redm[r][0], redm[r][1]), fmaxf(redm[r][2], redm[r][3]));
        alpha[r] = 2.0f / ((1.0f - M) + EPSF);
        basec[r] = 2.0f - alpha[r];
    }

    // phase 2: exp row-sums (batched butterfly)
    float s8[8];
#pragma unroll
    for (int r = 0; r < 8; r++) {
        float v[16];
        unpack8(d[r][0], v); unpack8(d[r][1], v + 8);
        float s = 0.f;
#pragma unroll
        for (int k = 0; k < 16; k++) s += __expf(fmaf(alpha[r], v[k], basec[r]));
        s8[r] = s;
    }
#pragma unroll
    for (int off = 32; off > 0; off >>= 1)
#pragma unroll
        for (int r = 0; r < 8; r++) s8[r] += __shfl_xor(s8[r], off);
    if (lane == 0)
#pragma unroll
        for (int r = 0; r < 8; r++) sval[r][wave] = s8[r];
    __syncthreads();

    // phase 3: beta + column logit-max
    float cmax[16];
#pragma unroll
    for (int k = 0; k < 16; k++) cmax[k] = -1e30f;
#pragma unroll
    for (int r = 0; r < 8; r++) {
        float S = sval[r][0] + sval[r][1] + sval[r][2] + sval[r][3];
        float beta = basec[r] - __logf(S);
        float v[16];
        unpack8(d[r][0], v); unpack8(d[r][1], v + 8);
#pragma unroll
        for (int k = 0; k < 16; k++) cmax[k] = fmaxf(cmax[k], fmaf(alpha[r], v[k], beta));
    }

    // store as bf16, packed uint4 (q = tid*8+k and 2048+tid*8+k)
    unsigned short* outp = partial + ((size_t)(n * 512 + chunk)) * HW;
    uint4 o0, o1;
    o0.x = pack2bf(cmax[0], cmax[1]);
    o0.y = pack2bf(cmax[2], cmax[3]);
    o0.z = pack2bf(cmax[4], cmax[5]);
    o0.w = pack2bf(cmax[6], cmax[7]);
    o1.x = pack2bf(cmax[8], cmax[9]);
    o1.y = pack2bf(cmax[10], cmax[11]);
    o1.z = pack2bf(cmax[12], cmax[13]);
    o1.w = pack2bf(cmax[14], cmax[15]);
    *(uint4*)(outp + tid * 8) = o0;
    *(uint4*)(outp + 2048 + tid * 8) = o1;
}

// ---------- K5a: column max over 32-chunk groups (coalesced uint4 reads) ----------
__global__ __launch_bounds__(256) void colmax1(const unsigned short* __restrict__ partial,
                                               float* __restrict__ partial2) {
    int n = blockIdx.z, cg = blockIdx.y;        // 16 chunk-groups of 32
    int q0 = blockIdx.x * 2048 + threadIdx.x * 8;  // 2 q-tiles
    const unsigned short* p = partial + ((size_t)(n * 512 + cg * 32)) * HW + q0;
    float mx[8];
#pragma unroll
    for (int k = 0; k < 8; k++) mx[k] = -1e30f;
    for (int c = 0; c < 32; c++) {
        uint4 u = *(const uint4*)(p + (size_t)c * HW);
        float v[8];
        unpack8(u, v);
#pragma unroll
        for (int k = 0; k < 8; k++) mx[k] = fmaxf(mx[k], v[k]);
    }
    float* o = partial2 + ((size_t)(n * 16 + cg)) * HW + q0;
#pragma unroll
    for (int k = 0; k < 8; k += 4) {
        float4 ov = {mx[k], mx[k + 1], mx[k + 2], mx[k + 3]};
        *(float4*)(o + k) = ov;
    }
}

// ---------- K5b: final column max over 16 groups, exp, sum over q ----------
__global__ __launch_bounds__(1024) void colfinal2(const float* __restrict__ partial2,
                                                  float* __restrict__ cxsum) {
    int n = blockIdx.x;
    int tid = threadIdx.x;
    const float* p = partial2 + (size_t)n * 16 * HW + tid * 4;
    float4 m = {-1e30f, -1e30f, -1e30f, -1e30f};
#pragma unroll
    for (int g = 0; g < 16; g++) {
        float4 v = *(const float4*)(p + (size_t)g * HW);
        m.x = fmaxf(m.x, v.x); m.y = fmaxf(m.y, v.y);
        m.z = fmaxf(m.z, v.z); m.w = fmaxf(m.w, v.w);
    }
    float s = __expf(m.x) + __expf(m.y) + __expf(m.z) + __expf(m.w);
    s = waveReduceSum(s);
    __shared__ float red[16];
    int lane = tid & 63, wave = tid >> 6;
    if (lane == 0) red[wave] = s;
    __syncthreads();
    if (tid == 0) {
        float S = 0.f;
        for (int w = 0; w < 16; w++) S += red[w];
        cxsum[n] = S;
    }
}

// ---------- K6: final loss ----------
__global__ void finalize(const float* __restrict__ cxsum, float* __restrict__ out) {
    if (threadIdx.x == 0 && blockIdx.x == 0) {
        float loss = 0.f;
        for (int n = 0; n < NB; n++) {
            float cx = cxsum[n] * (1.0f / 4096.0f);
            loss += -logf(cx + EPSF);
        }
        out[0] = loss * 0.25f;
    }
}

// ---------- launch ----------
extern "C" void kernel_launch(void* const* d_in, const int* in_sizes, int n_in,
                              void* d_out, int out_size, void* d_ws, size_t ws_size,
                              hipStream_t stream) {
    const float* x = (const float*)d_in[0];
    const float* y = (const float*)d_in[1];
    float* out = (float*)d_out;
    char* ws = (char*)d_ws;

    float* mu               = (float*)(ws + 0);                   // 1 KiB
    float* cxsum            = (float*)(ws + 1024);                // 16 B
    float* partial2         = (float*)(ws + 65536);               // 1 MiB
    unsigned short* Xn      = (unsigned short*)(ws + 2097152);    // 8 MiB
    unsigned short* Yn      = (unsigned short*)(ws + 10485760);   // 8 MiB
    unsigned short* partial = (unsigned short*)(ws + 2097152);    // 16 MiB bf16 (aliases Xn+Yn, used after gemm)
    unsigned short* Cos     = (unsigned short*)(ws + 18874368);   // 128 MiB

    mu_kernel<<<C, 256, 0, stream>>>(y, mu);
    prep_kernel<<<NROWS / TP, 256, 0, stream>>>(x, y, mu, Xn, Yn);
    gemm_cos<<<dim3(HW / 128, HW / 128, NB), 256, 0, stream>>>(Xn, Yn, Cos);
    rowcol<<<dim3(512, NB), 256, 0, stream>>>(Cos, partial);
    colmax1<<<dim3(2, 16, NB), 256, 0, stream>>>(partial, partial2);
    colfinal2<<<NB, 1024, 0, stream>>>(partial2, cxsum);
    finalize<<<1, 64, 0, stream>>>(cxsum, out);
}